// Round 6
// baseline (198.310 us; speedup 1.0000x reference)
//
#include <hip/hip_runtime.h>

#define EPS 1e-05f
#define ALPHA 0.05f

typedef _Float16 h2v __attribute__((ext_vector_type(2)));
typedef _Float16 f16x8 __attribute__((ext_vector_type(8)));
typedef float f32x16 __attribute__((ext_vector_type(16)));

__device__ __forceinline__ float rcp_f(float x){ return __builtin_amdgcn_rcpf(x); }
__device__ __forceinline__ float dot2(h2v a, h2v b, float c){
  return __builtin_amdgcn_fdot2(a, b, c, false);
}
__device__ __forceinline__ h2v uh(uint u){ return __builtin_bit_cast(h2v, u); }
__device__ __forceinline__ float uf(uint u){ return __builtin_bit_cast(float, u); }

#define LOG2E 1.4426950408889634f
#define LN2   0.6931471805599453f

__device__ __forceinline__ float fast_tanh(float x){
  float ax = fabsf(x);
  float e  = exp2f(ax * (-2.0f * LOG2E));
  float t  = (1.0f - e) * rcp_f(1.0f + e);
  return copysignf(t, x);
}
__device__ __forceinline__ float fast_sp(float x){
  float ax = fabsf(x);
  float e  = exp2f(ax * -LOG2E);
  return fmaxf(x, 0.0f) + log2f(1.0f + e) * LN2;
}
__device__ __forceinline__ float fast_sig(float x){
  float ax = fabsf(x);
  float e  = exp2f(ax * -LOG2E);
  float r  = rcp_f(1.0f + e);
  return x >= 0.0f ? r : e * r;
}
__device__ __forceinline__ float sig_from_sp(float sp){
  return 1.0f - exp2f(sp * -LOG2E);
}
__device__ __forceinline__ h2v mkh2(float a, float b){
  h2v r; r.x = (_Float16)a; r.y = (_Float16)b; return r;
}
__device__ __forceinline__ uint packh(float a, float b){
  ushort lo = __builtin_bit_cast(ushort, (_Float16)a);
  ushort hi = __builtin_bit_cast(ushort, (_Float16)b);
  return (uint)lo | ((uint)hi << 16);
}

// ================= fused kernel: stage + pack + yref + compute =================
// launch_bounds(512,2): arg2 = min blocks/CU; LDS ~72KB caps at 2 blocks/CU.
__global__ __launch_bounds__(512, 2) void holo_main(
    const float* __restrict__ X, const float* __restrict__ U,
    const float* __restrict__ xref,
    const float* __restrict__ fw1, const float* __restrict__ fb1,
    const float* __restrict__ fw2, const float* __restrict__ fb2,
    const float* __restrict__ fw3, const float* __restrict__ fb3,
    const float* __restrict__ gw,  const float* __restrict__ gb,
    const float* __restrict__ iw1, const float* __restrict__ ib1,
    const float* __restrict__ iw2, const float* __restrict__ ib2,
    const float* __restrict__ iw3, const float* __restrict__ ib3,
    const float* __restrict__ iw4, const float* __restrict__ ib4,
    const float* __restrict__ im2, const float* __restrict__ im3,
    const float* __restrict__ im4,
    float* __restrict__ out, int N)
{
  // ---- LDS (all rows 16B-aligned; pads are ZERO where dotted) ----
  __shared__ alignas(16) ushort sW2r[224*84]; // fw2 [224 rows][84 halves] (pad)
  __shared__ uint4 sW3E[224];   // 112 n-pair rows x 2: {p_d0..p_d5, fb2[n], fb2[n+1]}
  __shared__ uint4 sPW1B[80];   // fw1 row o: {w01,w23,w45, fb1[o]}
  __shared__ uint4 sPGB[36];    // gw  row o: {w01,w23,w45, gb[o]}
  __shared__ uint4 sPI1B[60];   // 30 p-rows x 2: {iw1[2p]w,b | iw1[2p+1]w,b}
  __shared__ uint4 sPI1C[60];   // 30 q-rows x 2: {packh(iw1[2q][d],iw1[2q+1][d]) d0..5, 0,0}
  __shared__ uint4 sPI3[240];   // 30 rows x 8: packh(iw3[r][2q],[2q+1]) q0..29, 0,0
  __shared__ uint4 sPI3C[240];  // 60 rows x 4: packh(iw3[2q][j],iw3[2q+1][j]) q0..14, 0
  __shared__ uint4 sPM2B[60];   // im2 row j: {w01,w23,w45, ib2[j]}
  __shared__ uint4 sPM2C[60];   // 30 q-rows x 2: {packh(im2[2q][d],im2[2q+1][d]) d0..5,0,0}
  __shared__ uint4 sPM3B[60];   // 30 rows x 2: {w01,w23,w45, ib3[r] | iw4[r],0,0,0}
  __shared__ uint4 sPM3C[30];   // 15 q-rows x 2: {packh(im3[2q][d],im3[2q+1][d]) d0..5,0,0}
  __shared__ uint  sPM4u[4];    // im4 pairs
  __shared__ alignas(16) uint sPI2Tu[1800]; // [30 p][60 j] packh(iw2[j][2p],[2p+1])
  __shared__ uint4 sPI2C[480];  // 60 k1-rows x 8: packh(iw2[2q][k1],iw2[2q+1][k1]) q0..29,0,0
  __shared__ float sFB3[6], sXREF[6], sIM4[6];
  __shared__ float sS1[60], sS2[60], sS3[30];
  __shared__ float sYREF, sIB4;

  const int t = threadIdx.x;
  const int T = 512;
  const int lane = t & 63;

  // ---- stage + pack from original weights ----
  for (int idx=t; idx<224*42; idx+=T){          // sW2r as u32 pairs
    int row = idx/42, c = idx%42, k = 2*c;
    uint v = 0;
    if (row < 200 && k < 80) v = packh(fw2[row*80+k], fw2[row*80+k+1]);
    ((uint*)sW2r)[idx] = v;
  }
  for (int idx=t; idx<896; idx+=T){             // sW3E
    int P = idx/8, c = idx%8, n = 2*P;
    uint v = 0;
    if (n < 200){
      if (c < 6)       v = packh(fw3[c*200+n], fw3[c*200+n+1]);
      else if (c == 6) v = __builtin_bit_cast(uint, fb2[n]);
      else             v = __builtin_bit_cast(uint, fb2[n+1]);
    }
    ((uint*)sW3E)[idx] = v;
  }
  for (int idx=t; idx<320; idx+=T){             // sPW1B
    int o = idx/4, c = idx%4;
    ((uint*)sPW1B)[idx] = (c<3) ? packh(fw1[o*6+2*c], fw1[o*6+2*c+1])
                                : __builtin_bit_cast(uint, fb1[o]);
  }
  for (int idx=t; idx<144; idx+=T){             // sPGB
    int o = idx/4, c = idx%4;
    ((uint*)sPGB)[idx] = (c<3) ? packh(gw[o*6+2*c], gw[o*6+2*c+1])
                               : __builtin_bit_cast(uint, gb[o]);
  }
  for (int idx=t; idx<240; idx+=T){             // sPI1B
    int p = idx/8, c = idx%8, sub = c/4, cc = c%4, nr = 2*p+sub;
    ((uint*)sPI1B)[idx] = (cc<3) ? packh(iw1[nr*6+2*cc], iw1[nr*6+2*cc+1])
                                 : __builtin_bit_cast(uint, ib1[nr]);
  }
  for (int idx=t; idx<240; idx+=T){             // sPI1C
    int q = idx/8, c = idx%8;
    ((uint*)sPI1C)[idx] = (c<6) ? packh(iw1[(2*q)*6+c], iw1[(2*q+1)*6+c]) : 0u;
  }
  for (int idx=t; idx<960; idx+=T){             // sPI3
    int r = idx/32, q = idx%32;
    ((uint*)sPI3)[idx] = (q<30) ? packh(iw3[r*60+2*q], iw3[r*60+2*q+1]) : 0u;
  }
  for (int idx=t; idx<960; idx+=T){             // sPI3C
    int j = idx/16, q = idx%16;
    ((uint*)sPI3C)[idx] = (q<15) ? packh(iw3[(2*q)*60+j], iw3[(2*q+1)*60+j]) : 0u;
  }
  for (int idx=t; idx<240; idx+=T){             // sPM2B
    int j = idx/4, c = idx%4;
    ((uint*)sPM2B)[idx] = (c<3) ? packh(im2[j*6+2*c], im2[j*6+2*c+1])
                                : __builtin_bit_cast(uint, ib2[j]);
  }
  for (int idx=t; idx<240; idx+=T){             // sPM2C
    int q = idx/8, c = idx%8;
    ((uint*)sPM2C)[idx] = (c<6) ? packh(im2[(2*q)*6+c], im2[(2*q+1)*6+c]) : 0u;
  }
  for (int idx=t; idx<240; idx+=T){             // sPM3B
    int r = idx/8, c = idx%8;
    uint v = 0;
    if (c < 3)       v = packh(im3[r*6+2*c], im3[r*6+2*c+1]);
    else if (c == 3) v = __builtin_bit_cast(uint, ib3[r]);
    else if (c == 4) v = __builtin_bit_cast(uint, iw4[r]);
    ((uint*)sPM3B)[idx] = v;
  }
  for (int idx=t; idx<120; idx+=T){             // sPM3C
    int q = idx/8, c = idx%8;
    ((uint*)sPM3C)[idx] = (c<6) ? packh(im3[(2*q)*6+c], im3[(2*q+1)*6+c]) : 0u;
  }
  for (int idx=t; idx<4; idx+=T)
    sPM4u[idx] = (idx<3) ? packh(im4[2*idx], im4[2*idx+1]) : 0u;
  for (int idx=t; idx<1800; idx+=T){            // sPI2Tu
    int p = idx/60, j = idx%60;
    sPI2Tu[idx] = packh(iw2[j*60+2*p], iw2[j*60+2*p+1]);
  }
  for (int idx=t; idx<1920; idx+=T){            // sPI2C
    int k1 = idx/32, q = idx%32;
    ((uint*)sPI2C)[idx] = (q<30) ? packh(iw2[(2*q)*60+k1], iw2[(2*q+1)*60+k1]) : 0u;
  }
  for (int k=t;k<6;k+=T){ sFB3[k]=fb3[k]; sIM4[k]=im4[k]; sXREF[k]=xref[k]; }
  if (t==0) sIB4=ib4[0];
  __syncthreads();

  // ---- cooperative yref = icnn(xref) from the SAME packed f16 weights ----
  {
    h2v xrp[3];
    #pragma unroll
    for (int p = 0; p < 3; p++) xrp[p] = mkh2(sXREF[2*p], sXREF[2*p+1]);
    if (t < 60){
      const uint* w = (const uint*)sPI1B + (t/2)*8 + (t&1)*4;
      float z = uf(w[3]);
      #pragma unroll
      for (int c = 0; c < 3; c++) z = dot2(uh(w[c]), xrp[c], z);
      sS1[t] = fast_sp(z);
    }
    __syncthreads();
    if (t < 60){
      const uint* m = (const uint*)sPM2B + t*4;
      float z = uf(m[3]);
      #pragma unroll
      for (int c = 0; c < 3; c++) z = dot2(uh(m[c]), xrp[c], z);
      for (int p = 0; p < 30; p++)
        z = dot2(uh(sPI2Tu[p*60+t]), mkh2(sS1[2*p], sS1[2*p+1]), z);
      sS2[t] = fast_sp(z);
    }
    __syncthreads();
    if (t < 30){
      const uint* m = (const uint*)sPM3B + t*8;
      float z = uf(m[3]);
      #pragma unroll
      for (int c = 0; c < 3; c++) z = dot2(uh(m[c]), xrp[c], z);
      const uint* prow = (const uint*)sPI3 + t*32;
      for (int q = 0; q < 30; q++)
        z = dot2(uh(prow[q]), mkh2(sS2[2*q], sS2[2*q+1]), z);
      sS3[t] = fast_sp(z);
    }
    __syncthreads();
    if (t == 0){
      float y = sIB4;
      #pragma unroll
      for (int p = 0; p < 3; p++) y = dot2(uh(sPM4u[p]), xrp[p], y);
      for (int j = 0; j < 30; j++) y = fmaf(uf(((const uint*)sPM3B)[j*8+4]), sS3[j], y);
      sYREF = y;
    }
    __syncthreads();
  }

  // ---- per-thread sample compute (guarded loads/stores, full-wave execution) ----
  const int i = blockIdx.x * blockDim.x + t;
  const bool valid = (i < N);

  float x[6]; h2v xp[3];
  #pragma unroll
  for (int k = 0; k < 6; k++) x[k] = valid ? X[(long)i*6 + k] : 0.0f;
  #pragma unroll
  for (int p = 0; p < 3; p++) xp[p] = mkh2(x[2*p], x[2*p+1]);

  // ============ FNN layer 1: 6 -> 80, tanh (b128 weight rows) ============
  uint h1u[40];
  #pragma unroll
  for (int o = 0; o < 80; o += 2){
    uint4 wa = sPW1B[o], wb = sPW1B[o+1];
    float z0 = uf(wa.w), z1 = uf(wb.w);
    z0 = dot2(uh(wa.x), xp[0], z0); z0 = dot2(uh(wa.y), xp[1], z0); z0 = dot2(uh(wa.z), xp[2], z0);
    z1 = dot2(uh(wb.x), xp[0], z1); z1 = dot2(uh(wb.y), xp[1], z1); z1 = dot2(uh(wb.z), xp[2], z1);
    h1u[o/2] = packh(fast_tanh(z0), fast_tanh(z1));
  }

  // ============ FNN L2+L3 via MFMA (32x32x16 f16) ============
  const int hh = lane >> 5;
  const int l31 = lane & 31;

  // B-fragments from h1 via ds_bpermute (pull sample (nt*32+l31)'s h1 regs)
  uint bf0[5][4], bf1[5][4];
  {
    int a0 = 4 * l31;          // nt = 0
    int a1 = 4 * (32 + l31);   // nt = 1
    #pragma unroll
    for (int kt = 0; kt < 5; kt++){
      #pragma unroll
      for (int q = 0; q < 4; q++){
        int lo0 = __builtin_amdgcn_ds_bpermute(a0, (int)h1u[kt*8 + q]);
        int hi0 = __builtin_amdgcn_ds_bpermute(a0, (int)h1u[kt*8 + 4 + q]);
        bf0[kt][q] = hh ? (uint)hi0 : (uint)lo0;
        int lo1 = __builtin_amdgcn_ds_bpermute(a1, (int)h1u[kt*8 + q]);
        int hi1 = __builtin_amdgcn_ds_bpermute(a1, (int)h1u[kt*8 + 4 + q]);
        bf1[kt][q] = hh ? (uint)hi1 : (uint)lo1;
      }
    }
  }

  float fp0[6] = {0.f,0.f,0.f,0.f,0.f,0.f};
  float fp1[6] = {0.f,0.f,0.f,0.f,0.f,0.f};
  for (int mt = 0; mt < 7; mt++){
    const int row = mt*32 + l31;
    f16x8 af[5];
    #pragma unroll
    for (int kt = 0; kt < 5; kt++){
      const ushort* wp = &sW2r[row*84 + kt*16 + 8*hh];
      uint2 w0 = *(const uint2*)wp;
      uint2 w1 = *(const uint2*)(wp + 4);
      uint4 au; au.x = w0.x; au.y = w0.y; au.z = w1.x; au.w = w1.y;
      af[kt] = __builtin_bit_cast(f16x8, au);
    }
    f32x16 acc0 = {0,0,0,0,0,0,0,0,0,0,0,0,0,0,0,0};
    f32x16 acc1 = {0,0,0,0,0,0,0,0,0,0,0,0,0,0,0,0};
    #pragma unroll
    for (int kt = 0; kt < 5; kt++){
      uint4 b0u; b0u.x=bf0[kt][0]; b0u.y=bf0[kt][1]; b0u.z=bf0[kt][2]; b0u.w=bf0[kt][3];
      uint4 b1u; b1u.x=bf1[kt][0]; b1u.y=bf1[kt][1]; b1u.z=bf1[kt][2]; b1u.w=bf1[kt][3];
      acc0 = __builtin_amdgcn_mfma_f32_32x32x16_f16(af[kt], __builtin_bit_cast(f16x8, b0u), acc0, 0, 0, 0);
      acc1 = __builtin_amdgcn_mfma_f32_32x32x16_f16(af[kt], __builtin_bit_cast(f16x8, b1u), acc1, 0, 0, 0);
    }
    // epilogue: neuron-PAIR processing; biases + tanh + packed-W3 dot2 reduction
    #pragma unroll
    for (int c = 0; c < 4; c++){
      #pragma unroll
      for (int b0h = 0; b0h < 2; b0h++){
        const int r0 = 4*c + 2*b0h;          // acc regs r0, r0+1 = neurons n, n+1
        const int P  = mt*16 + 4*c + 2*hh + b0h;
        uint4 wa = sW3E[P*2], wb = sW3E[P*2+1];
        float bA = uf(wb.z), bB = uf(wb.w);
        h2v tp0 = mkh2(fast_tanh(acc0[r0] + bA), fast_tanh(acc0[r0+1] + bB));
        h2v tp1 = mkh2(fast_tanh(acc1[r0] + bA), fast_tanh(acc1[r0+1] + bB));
        fp0[0] = dot2(uh(wa.x), tp0, fp0[0]); fp1[0] = dot2(uh(wa.x), tp1, fp1[0]);
        fp0[1] = dot2(uh(wa.y), tp0, fp0[1]); fp1[1] = dot2(uh(wa.y), tp1, fp1[1]);
        fp0[2] = dot2(uh(wa.z), tp0, fp0[2]); fp1[2] = dot2(uh(wa.z), tp1, fp1[2]);
        fp0[3] = dot2(uh(wa.w), tp0, fp0[3]); fp1[3] = dot2(uh(wa.w), tp1, fp1[3]);
        fp0[4] = dot2(uh(wb.x), tp0, fp0[4]); fp1[4] = dot2(uh(wb.x), tp1, fp1[4]);
        fp0[5] = dot2(uh(wb.y), tp0, fp0[5]); fp1[5] = dot2(uh(wb.y), tp1, fp1[5]);
      }
    }
  }
  float f[6];
  #pragma unroll
  for (int d = 0; d < 6; d++){
    float s0 = fp0[d] + __shfl_xor(fp0[d], 32, 64);
    float s1 = fp1[d] + __shfl_xor(fp1[d], 32, 64);
    f[d] = sFB3[d] + (hh ? s1 : s0);
  }

  // ============ ICNN forward ============
  float c2[60];
  #pragma unroll
  for (int j = 0; j < 60; j++){
    uint4 m = sPM2B[j];
    float z = uf(m.w);
    z = dot2(uh(m.x), xp[0], z); z = dot2(uh(m.y), xp[1], z); z = dot2(uh(m.z), xp[2], z);
    c2[j] = z;
  }
  for (int p = 0; p < 30; p++){           // k1 pairs, streamed
    uint4 wA = sPI1B[2*p], wB = sPI1B[2*p+1];
    float za = uf(wA.w), zb = uf(wB.w);
    za = dot2(uh(wA.x), xp[0], za); za = dot2(uh(wA.y), xp[1], za); za = dot2(uh(wA.z), xp[2], za);
    zb = dot2(uh(wB.x), xp[0], zb); zb = dot2(uh(wB.y), xp[1], zb); zb = dot2(uh(wB.z), xp[2], zb);
    h2v s = mkh2(fast_sp(za), fast_sp(zb));
    const uint* rowp = sPI2Tu + p*60;
    #pragma unroll
    for (int jj = 0; jj < 15; jj++){
      uint4 v = *(const uint4*)(rowp + jj*4);
      c2[4*jj+0] = dot2(uh(v.x), s, c2[4*jj+0]);
      c2[4*jj+1] = dot2(uh(v.y), s, c2[4*jj+1]);
      c2[4*jj+2] = dot2(uh(v.z), s, c2[4*jj+2]);
      c2[4*jj+3] = dot2(uh(v.w), s, c2[4*jj+3]);
    }
  }
  h2v c2p[32];
  #pragma unroll
  for (int j = 0; j < 60; j += 2)
    c2p[j/2] = mkh2(fast_sp(c2[j]), fast_sp(c2[j+1]));
  c2p[30] = mkh2(0.f, 0.f); c2p[31] = mkh2(0.f, 0.f);

  // layer 3 fwd + y + g3
  float y = sIB4;
  #pragma unroll
  for (int p = 0; p < 3; p++) y = dot2(uh(sPM4u[p]), xp[p], y);
  float ac[6];
  #pragma unroll
  for (int d = 0; d < 6; d++) ac[d] = sIM4[d];
  float g3[30];
  #pragma unroll
  for (int i3 = 0; i3 < 30; i3++){
    uint4 m0 = sPM3B[2*i3], m1 = sPM3B[2*i3+1];
    float z = uf(m0.w);
    z = dot2(uh(m0.x), xp[0], z); z = dot2(uh(m0.y), xp[1], z); z = dot2(uh(m0.z), xp[2], z);
    const uint4* prow = sPI3 + i3*8;
    #pragma unroll
    for (int q4 = 0; q4 < 8; q4++){
      uint4 v = prow[q4];
      z = dot2(uh(v.x), c2p[4*q4+0], z);
      z = dot2(uh(v.y), c2p[4*q4+1], z);
      z = dot2(uh(v.z), c2p[4*q4+2], z);
      z = dot2(uh(v.w), c2p[4*q4+3], z);
    }
    float sp3 = fast_sp(z);
    float w4  = uf(m1.x);
    y = fmaf(w4, sp3, y);
    g3[i3] = w4 * sig_from_sp(sp3);
  }
  h2v g3p[16];
  #pragma unroll
  for (int q = 0; q < 15; q++) g3p[q] = mkh2(g3[2*q], g3[2*q+1]);
  g3p[15] = mkh2(0.f, 0.f);
  #pragma unroll
  for (int q = 0; q < 15; q++){
    uint4 a = sPM3C[2*q], b = sPM3C[2*q+1];
    ac[0] = dot2(uh(a.x), g3p[q], ac[0]);
    ac[1] = dot2(uh(a.y), g3p[q], ac[1]);
    ac[2] = dot2(uh(a.z), g3p[q], ac[2]);
    ac[3] = dot2(uh(a.w), g3p[q], ac[3]);
    ac[4] = dot2(uh(b.x), g3p[q], ac[4]);
    ac[5] = dot2(uh(b.y), g3p[q], ac[5]);
  }

  // bwd g2
  h2v g2p[32];
  #pragma unroll
  for (int jp = 0; jp < 30; jp++){
    const uint4* r0p = sPI3C + (2*jp)*4;
    const uint4* r1p = sPI3C + (2*jp+1)*4;
    float ta = 0.0f, tb = 0.0f;
    #pragma unroll
    for (int q4 = 0; q4 < 4; q4++){
      uint4 v0 = r0p[q4], v1 = r1p[q4];
      ta = dot2(uh(v0.x), g3p[4*q4+0], ta);
      ta = dot2(uh(v0.y), g3p[4*q4+1], ta);
      ta = dot2(uh(v0.z), g3p[4*q4+2], ta);
      ta = dot2(uh(v0.w), g3p[4*q4+3], ta);
      tb = dot2(uh(v1.x), g3p[4*q4+0], tb);
      tb = dot2(uh(v1.y), g3p[4*q4+1], tb);
      tb = dot2(uh(v1.z), g3p[4*q4+2], tb);
      tb = dot2(uh(v1.w), g3p[4*q4+3], tb);
    }
    h2v sp = c2p[jp];
    ta *= sig_from_sp((float)sp.x);
    tb *= sig_from_sp((float)sp.y);
    h2v tp = mkh2(ta, tb);
    g2p[jp] = tp;
    uint4 a = sPM2C[2*jp], b = sPM2C[2*jp+1];
    ac[0] = dot2(uh(a.x), tp, ac[0]);
    ac[1] = dot2(uh(a.y), tp, ac[1]);
    ac[2] = dot2(uh(a.z), tp, ac[2]);
    ac[3] = dot2(uh(a.w), tp, ac[3]);
    ac[4] = dot2(uh(b.x), tp, ac[4]);
    ac[5] = dot2(uh(b.y), tp, ac[5]);
  }
  g2p[30] = mkh2(0.f, 0.f); g2p[31] = mkh2(0.f, 0.f);

  // bwd g1 (streamed; z1 recomputed)
  for (int p = 0; p < 30; p++){
    uint4 wA = sPI1B[2*p], wB = sPI1B[2*p+1];
    float za = uf(wA.w), zb = uf(wB.w);
    za = dot2(uh(wA.x), xp[0], za); za = dot2(uh(wA.y), xp[1], za); za = dot2(uh(wA.z), xp[2], za);
    zb = dot2(uh(wB.x), xp[0], zb); zb = dot2(uh(wB.y), xp[1], zb); zb = dot2(uh(wB.z), xp[2], zb);
    const uint4* c0 = sPI2C + (2*p)*8;
    const uint4* c1 = sPI2C + (2*p+1)*8;
    float ta = 0.0f, tb = 0.0f;
    #pragma unroll
    for (int q4 = 0; q4 < 8; q4++){
      uint4 v0 = c0[q4], v1 = c1[q4];
      ta = dot2(uh(v0.x), g2p[4*q4+0], ta);
      ta = dot2(uh(v0.y), g2p[4*q4+1], ta);
      ta = dot2(uh(v0.z), g2p[4*q4+2], ta);
      ta = dot2(uh(v0.w), g2p[4*q4+3], ta);
      tb = dot2(uh(v1.x), g2p[4*q4+0], tb);
      tb = dot2(uh(v1.y), g2p[4*q4+1], tb);
      tb = dot2(uh(v1.z), g2p[4*q4+2], tb);
      tb = dot2(uh(v1.w), g2p[4*q4+3], tb);
    }
    ta *= fast_sig(za); tb *= fast_sig(zb);
    h2v tp = mkh2(ta, tb);
    uint4 a = sPI1C[2*p], b = sPI1C[2*p+1];
    ac[0] = dot2(uh(a.x), tp, ac[0]);
    ac[1] = dot2(uh(a.y), tp, ac[1]);
    ac[2] = dot2(uh(a.z), tp, ac[2]);
    ac[3] = dot2(uh(a.w), tp, ac[3]);
    ac[4] = dot2(uh(b.x), tp, ac[4]);
    ac[5] = dot2(uh(b.y), tp, ac[5]);
  }

  // ============ V, dV ============
  float hdiff = y - sYREF;
  float sigma = (hdiff >= 1.0f) ? (hdiff - 0.5f) : ((hdiff > 0.0f) ? 0.5f*hdiff*hdiff : 0.0f);
  float sigp  = (hdiff >= 1.0f) ? 1.0f          : ((hdiff > 0.0f) ? hdiff             : 0.0f);
  float dx2 = 0.0f;
  float dV[6];
  #pragma unroll
  for (int d = 0; d < 6; d++){
    float dx = x[d] - sXREF[d];
    dx2 = fmaf(dx, dx, dx2);
    dV[d] = fmaf(sigp, ac[d], 2.0f*EPS*dx);
  }
  float V = sigma + EPS*dx2;

  float sc = ALPHA * V;
  #pragma unroll
  for (int d = 0; d < 6; d++) sc = fmaf(dV[d], f[d], sc);

  // ============ GNN + combine ============
  float u[6];
  #pragma unroll
  for (int m = 0; m < 6; m++) u[m] = valid ? U[(long)i*6 + m] : 0.0f;
  float am[6] = {0.f,0.f,0.f,0.f,0.f,0.f};
  float gU[6];
  #pragma unroll
  for (int d = 0; d < 6; d++){
    float acc = 0.0f;
    #pragma unroll
    for (int m = 0; m < 6; m++){
      int o = d*6 + m;
      uint4 g4 = sPGB[o];
      float g = uf(g4.w);
      g = dot2(uh(g4.x), xp[0], g); g = dot2(uh(g4.y), xp[1], g); g = dot2(uh(g4.z), xp[2], g);
      am[m] = fmaf(dV[d], g, am[m]);
      acc   = fmaf(g, u[m], acc);
    }
    gU[d] = acc;
  }
  #pragma unroll
  for (int m = 0; m < 6; m++) sc -= fabsf(am[m]);

  float n2 = 0.0f;
  #pragma unroll
  for (int d = 0; d < 6; d++) n2 = fmaf(dV[d], dV[d], n2);
  float r = fmaxf(sc, 0.0f) * rcp_f(n2);

  if (valid){
    #pragma unroll
    for (int d = 0; d < 6; d++)
      out[(long)i*6 + d] = f[d] - dV[d]*r + gU[d];
  }
}

extern "C" void kernel_launch(void* const* d_in, const int* in_sizes, int n_in,
                              void* d_out, int out_size, void* d_ws, size_t ws_size,
                              hipStream_t stream)
{
  const float* X    = (const float*)d_in[0];
  const float* U    = (const float*)d_in[1];
  const float* xref = (const float*)d_in[2];
  const float* fw1  = (const float*)d_in[3];
  const float* fb1  = (const float*)d_in[4];
  const float* fw2  = (const float*)d_in[5];
  const float* fb2  = (const float*)d_in[6];
  const float* fw3  = (const float*)d_in[7];
  const float* fb3  = (const float*)d_in[8];
  const float* gw   = (const float*)d_in[9];
  const float* gb   = (const float*)d_in[10];
  const float* iw1  = (const float*)d_in[11];
  const float* ib1  = (const float*)d_in[12];
  const float* iw2  = (const float*)d_in[13];
  const float* ib2  = (const float*)d_in[14];
  const float* iw3  = (const float*)d_in[15];
  const float* ib3  = (const float*)d_in[16];
  const float* iw4  = (const float*)d_in[17];
  const float* ib4  = (const float*)d_in[18];
  const float* im2  = (const float*)d_in[19];
  const float* im3  = (const float*)d_in[20];
  const float* im4  = (const float*)d_in[21];

  float* out = (float*)d_out;
  int N = in_sizes[0] / 6;

  int threads = 512;
  int blocks  = (N + threads - 1) / threads;
  holo_main<<<blocks, threads, 0, stream>>>(X, U, xref,
      fw1, fb1, fw2, fb2, fw3, fb3, gw, gb,
      iw1, ib1, iw2, ib2, iw3, ib3, iw4, ib4, im2, im3, im4,
      out, N);
}